// Round 18
// baseline (31.946 us; speedup 1.0000x reference)
//
#include <hip/hip_runtime.h>

#define B_N   2048
#define LQ    10
#define LH    150

typedef float pf2 __attribute__((ext_vector_type(2)));

// ws float layout:
//   [0..17] eff_w   [18] eff_b   [19..27] fw
//   [30..119]  qwpk: float2[45] {q_w[2ap][t], q_w[2ap+1][t]}, idx=ap*9+t
//   [120..209] wpk:  float2[45] {w[2ap][t],  w[2ap+1][t]},   idx=ap*9+t
#define QWPK 30
#define WPK  120

// ---------------- pre-kernel (1 block x 256 thr) — R16-verified ----------------
__global__ __launch_bounds__(256) void vin_precompute(
    const float* __restrict__ h_w, const float* __restrict__ h_b,
    const float* __restrict__ r_w, const float* __restrict__ q_w,
    const float* __restrict__ w,   const float* __restrict__ fc_w,
    float* __restrict__ ws)
{
    __shared__ float l[3000];   // [0,2700) h_w, [2700,2850) h_b, [2850,3000) r_w
    const int t = threadIdx.x;
    #pragma unroll
    for (int k = 0; k < 11; ++k) {
        int idx = t + (k << 8);
        if (idx < 2700) l[idx] = h_w[idx];
    }
    if (t < 150) { l[2700 + t] = h_b[t]; l[2850 + t] = r_w[t]; }
    __syncthreads();

    if (t < 152) {
        const int tap = t >> 3, j = t & 7;
        float acc = 0.f;
        for (int h = j; h < LH; h += 8)
            acc += l[2850 + h] * (tap < 18 ? l[h * 18 + tap] : l[2700 + h]);
        acc += __shfl_down(acc, 4, 8);
        acc += __shfl_down(acc, 2, 8);
        acc += __shfl_down(acc, 1, 8);
        if (j == 0) ws[tap] = acc;
    } else if (t < 161) {
        const int tt = t - 152;
        float acc = 0.f;
        #pragma unroll
        for (int a = 0; a < LQ; ++a) acc += fc_w[a] * w[a * 9 + tt];
        ws[19 + tt] = acc;
    } else if (t < 206) {
        const int idx = t - 161, ap = idx / 9, tt = idx - ap * 9;
        ws[QWPK + 2 * idx]     = q_w[(2 * ap)     * 9 + tt];
        ws[QWPK + 2 * idx + 1] = q_w[(2 * ap + 1) * 9 + tt];
    } else if (t < 251) {
        const int idx = t - 206, ap = idx / 9, tt = idx - ap * 9;
        ws[WPK + 2 * idx]     = w[(2 * ap)     * 9 + tt];
        ws[WPK + 2 * idx + 1] = w[(2 * ap + 1) * 9 + tt];
    }
}

// ---------------- main kernel ----------------
// ONE WAVE handles TWO batch elements (1024 blocks x 64 thr, 1 wave/SIMD).
// lane = rg*16 + c; rg owns pixel rows 4rg..4rg+3, col c — for BOTH batches.
//
// Rationale (R17 post-mortem): at 2 same-code waves/SIMD the waves stall on
// their ds_bpermute halos in lockstep -> SIMD idles (VALUBusy 35-50%).
// Here a single wave interleaves two independent batches: when batch A's
// shfl is in flight, batch B's 20 independent pk_fma chains keep issuing.
// __launch_bounds__(64,1) lifts the VGPR cap to fit qr2[2][4][5] (~80 regs).
// LDS: X only, per batch: bt*1296 + ch*648 + (row+1)*36 + (col+1).
// All register arrays indexed with compile-time constants (round-4 lesson).
#define ST    36
#define XSZ   1296
#define SMEMN 2592

__device__ __forceinline__ float dpp_left(float x) {   // col c-1; 0 at c==0
    return __int_as_float(__builtin_amdgcn_update_dpp(
        0, __float_as_int(x), 0x111, 0xF, 0xF, true));  // row_shr:1
}
__device__ __forceinline__ float dpp_right(float x) {  // col c+1; 0 at c==15
    return __int_as_float(__builtin_amdgcn_update_dpp(
        0, __float_as_int(x), 0x101, 0xF, 0xF, true));  // row_shl:1
}

__global__ __launch_bounds__(64, 1) void vin_kernel(
    const float* __restrict__ X,   const float* __restrict__ S1,
    const float* __restrict__ S2,  const float* __restrict__ fcw,
    const float* __restrict__ ws,  float* __restrict__ out)
{
    __shared__ float smem[SMEMN];

    const int lane = threadIdx.x;
    const int rg   = lane >> 4;
    const int c    = lane & 15;
    const int b0   = 2 * blockIdx.x;
    const int b1   = b0 + 1;

    // ---- issue all global loads first ----
    const float* X0 = X + (size_t)b0 * 512;
    const float* X1 = X + (size_t)b1 * 512;
    float xr0[8], xr1[8];
    #pragma unroll
    for (int k = 0; k < 8; ++k) { xr0[k] = X0[lane + (k << 6)]; xr1[k] = X1[lane + (k << 6)]; }
    const float s1fA = S1[b0], s2fA = S2[b0];
    const float s1fB = S1[b1], s2fB = S2[b1];

    // ---- collapsed weights via uniform s_loads ----
    float ew[19];
    #pragma unroll
    for (int tt = 0; tt < 19; ++tt) ew[tt] = ws[tt];

    // ---- border-zero both batches' X regions (disjoint from interior) ----
    #pragma unroll
    for (int bt = 0; bt < 2; ++bt)
        #pragma unroll
        for (int ch = 0; ch < 2; ++ch) {
            float* Bc = smem + bt * XSZ + ch * 648;
            if (lane < 18)      { Bc[lane] = 0.f; Bc[17 * ST + lane] = 0.f; }
            else if (lane < 34) { const int r = lane - 17; Bc[r * ST] = 0.f; Bc[r * ST + 17] = 0.f; }
        }

    // ---- stage X interiors ----
    #pragma unroll
    for (int k = 0; k < 8; ++k) {
        int e = lane + (k << 6);
        int ch = e >> 8, rem = e & 255;
        const int off = ch * 648 + ((rem >> 4) + 1) * ST + (rem & 15) + 1;
        smem[off]       = xr0[k];
        smem[XSZ + off] = xr1[k];
    }
    __syncthreads();                       // single prologue barrier

    // ---- r = conv3x3(X, eff_w) + eff_b, both batches, in registers ----
    float rrA[4], rrB[4];
    #pragma unroll
    for (int bt = 0; bt < 2; ++bt) {
        const float* xb = smem + bt * XSZ + (rg << 2) * ST + c;
        float xt[2][6][3];
        #pragma unroll
        for (int ch = 0; ch < 2; ++ch)
            #pragma unroll
            for (int dy = 0; dy < 6; ++dy)
                #pragma unroll
                for (int dx = 0; dx < 3; ++dx)
                    xt[ch][dy][dx] = xb[ch * 648 + dy * ST + dx];
        #pragma unroll
        for (int k = 0; k < 4; ++k) {
            float acc = ew[18];
            #pragma unroll
            for (int ch = 0; ch < 2; ++ch)
                #pragma unroll
                for (int ky = 0; ky < 3; ++ky)
                    #pragma unroll
                    for (int kx = 0; kx < 3; ++kx)
                        acc += xt[ch][k + ky][kx] * ew[ch * 9 + ky * 3 + kx];
            if (bt == 0) rrA[k] = acc; else rrB[k] = acc;
        }
    }

    const bool top0 = (rg == 0), bot0 = (rg == 3);
    const int  upL  = (lane - 16) & 63;
    const int  dnL  = (lane + 16) & 63;

    // HALO: Sx[j] = own-col value at pixel row 4rg-1+j; Lx/Rx = cols c-1/c+1.
#define HALO_B(Sx, Lx, Rx, v0_, v1_, v2_, v3_)                   \
    {                                                            \
        float t_ = __shfl((v3_), upL, 64);                       \
        float b_ = __shfl((v0_), dnL, 64);                       \
        Sx[0] = top0 ? 0.f : t_;                                 \
        Sx[1] = (v0_); Sx[2] = (v1_); Sx[3] = (v2_); Sx[4] = (v3_); \
        Sx[5] = bot0 ? 0.f : b_;                                 \
        _Pragma("unroll")                                        \
        for (int j = 0; j < 6; ++j) {                            \
            Lx[j] = dpp_left(Sx[j]);                             \
            Rx[j] = dpp_right(Sx[j]);                            \
        }                                                        \
    }

    float SA[6], LA[6], RA[6], SB[6], LB[6], RB[6];
    HALO_B(SA, LA, RA, rrA[0], rrA[1], rrA[2], rrA[3])
    HALO_B(SB, LB, RB, rrB[0], rrB[1], rrB[2], rrB[3])

    const pf2* qwp = (const pf2*)(ws + QWPK);
    const pf2* wpk = (const pf2*)(ws + WPK);

    // ---- qr2[bt][k][ap] = packed conv3x3(r, q_w) (iteration-invariant) ----
    pf2 qr2[2][4][5];
    #pragma unroll
    for (int bt = 0; bt < 2; ++bt)
        #pragma unroll
        for (int k = 0; k < 4; ++k)
            #pragma unroll
            for (int ap = 0; ap < 5; ++ap) {
                pf2 acc = {0.f, 0.f};
                #pragma unroll
                for (int dy = 0; dy < 3; ++dy) {
                    const float tl = (bt == 0) ? LA[k + dy] : LB[k + dy];
                    const float ts = (bt == 0) ? SA[k + dy] : SB[k + dy];
                    const float tr = (bt == 0) ? RA[k + dy] : RB[k + dy];
                    pf2 vl = {tl, tl}, vs = {ts, ts}, vr = {tr, tr};
                    acc = __builtin_elementwise_fma(vl, qwp[ap * 9 + dy * 3 + 0], acc);
                    acc = __builtin_elementwise_fma(vs, qwp[ap * 9 + dy * 3 + 1], acc);
                    acc = __builtin_elementwise_fma(vr, qwp[ap * 9 + dy * 3 + 2], acc);
                }
                qr2[bt][k][ap] = acc;
            }

    // ---- v0 = max over 10 actions, both batches ----
    float vA[4], vB[4];
    #pragma unroll
    for (int k = 0; k < 4; ++k) {
        pf2 mA = __builtin_elementwise_max(
                     __builtin_elementwise_max(qr2[0][k][0], qr2[0][k][1]),
                     __builtin_elementwise_max(qr2[0][k][2], qr2[0][k][3]));
        mA = __builtin_elementwise_max(mA, qr2[0][k][4]);
        vA[k] = fmaxf(mA.x, mA.y);
        pf2 mB = __builtin_elementwise_max(
                     __builtin_elementwise_max(qr2[1][k][0], qr2[1][k][1]),
                     __builtin_elementwise_max(qr2[1][k][2], qr2[1][k][3]));
        mB = __builtin_elementwise_max(mB, qr2[1][k][4]);
        vB[k] = fmaxf(mB.x, mB.y);
    }

    // one VI sub-step for one batch (arrays indexed by unrolled consts only)
#define VSTEP_B(BT, Sx, Lx, Rx, vx)                                           \
    {                                                                         \
        _Pragma("unroll")                                                     \
        for (int k = 0; k < 4; ++k) {                                         \
            pf2 a_[5];                                                        \
            _Pragma("unroll")                                                 \
            for (int ap = 0; ap < 5; ++ap) a_[ap] = qr2[BT][k][ap];           \
            _Pragma("unroll")                                                 \
            for (int dy = 0; dy < 3; ++dy) {                                  \
                const float tl = Lx[k + dy], ts = Sx[k + dy], tr = Rx[k + dy];\
                pf2 vl = {tl, tl}, vs = {ts, ts}, vr = {tr, tr};              \
                _Pragma("unroll")                                             \
                for (int ap = 0; ap < 5; ++ap) {                              \
                    a_[ap] = __builtin_elementwise_fma(vl, wpk[ap * 9 + dy * 3 + 0], a_[ap]); \
                    a_[ap] = __builtin_elementwise_fma(vs, wpk[ap * 9 + dy * 3 + 1], a_[ap]); \
                    a_[ap] = __builtin_elementwise_fma(vr, wpk[ap * 9 + dy * 3 + 2], a_[ap]); \
                }                                                             \
            }                                                                 \
            pf2 m = __builtin_elementwise_max(                                \
                        __builtin_elementwise_max(a_[0], a_[1]),              \
                        __builtin_elementwise_max(a_[2], a_[3]));             \
            m = __builtin_elementwise_max(m, a_[4]);                          \
            vx[k] = fmaxf(m.x, m.y);                                          \
        }                                                                     \
    }

    // ---- 19 VI sweeps: both batches per iteration; halos issued together
    // so one batch's FMA stream covers the other's shfl latency ----
    #pragma unroll 1
    for (int it = 0; it < 19; ++it) {
        HALO_B(SA, LA, RA, vA[0], vA[1], vA[2], vA[3])
        HALO_B(SB, LB, RB, vB[0], vB[1], vB[2], vB[3])
        VSTEP_B(0, SA, LA, RA, vA)
        VSTEP_B(1, SB, LB, RB, vB)
    }

    // ---- final halos for the output conv taps ----
    HALO_B(SA, LA, RA, vA[0], vA[1], vA[2], vA[3])
    HALO_B(SB, LB, RB, vB[0], vB[1], vB[2], vB[3])

    // ---- epilogue per batch: conv(fw) + fc-dot at (s1,s2) only ----
    float fw[9];
    #pragma unroll
    for (int tt = 0; tt < 9; ++tt) fw[tt] = ws[19 + tt];

#define EPILOGUE_B(BT, Sx, Lx, Rx, s1f_, s2f_, bidx)                          \
    {                                                                         \
        int s1 = (int)floorf(((s1f_) + 50.0f) / 6.25f);                       \
        int s2 = (int)floorf(((s2f_) + 50.0f) / 6.25f);                       \
        s1 = min(max(s1, 0), 15);                                             \
        s2 = min(max(s2, 0), 15);                                             \
        if (rg == (s1 >> 2) && c == s2) {                                     \
            float d_[4];                                                      \
            _Pragma("unroll")                                                 \
            for (int k = 0; k < 4; ++k) {                                     \
                pf2 p = {0.f, 0.f};                                           \
                _Pragma("unroll")                                             \
                for (int ap = 0; ap < 5; ++ap) {                              \
                    const pf2 fcp = *(const pf2*)(fcw + 2 * ap);              \
                    p = __builtin_elementwise_fma(qr2[BT][k][ap], fcp, p);    \
                }                                                             \
                d_[k] = p.x + p.y;                                            \
            }                                                                 \
            float g0 = d_[0], g1 = d_[1], g2 = d_[2], g3 = d_[3];             \
            _Pragma("unroll")                                                 \
            for (int dy = 0; dy < 3; ++dy) {                                  \
                const float f0 = fw[dy * 3 + 0], f1 = fw[dy * 3 + 1], f2 = fw[dy * 3 + 2]; \
                g0 += Lx[0 + dy] * f0; g0 += Sx[0 + dy] * f1; g0 += Rx[0 + dy] * f2; \
                g1 += Lx[1 + dy] * f0; g1 += Sx[1 + dy] * f1; g1 += Rx[1 + dy] * f2; \
                g2 += Lx[2 + dy] * f0; g2 += Sx[2 + dy] * f1; g2 += Rx[2 + dy] * f2; \
                g3 += Lx[3 + dy] * f0; g3 += Sx[3 + dy] * f1; g3 += Rx[3 + dy] * f2; \
            }                                                                 \
            const int kk = s1 & 3;                                            \
            float logit = (kk == 0) ? g0 : (kk == 1) ? g1 : (kk == 2) ? g2 : g3; \
            out[bidx]       = logit;                                          \
            out[B_N + bidx] = 1.0f;                                           \
        }                                                                     \
    }

    EPILOGUE_B(0, SA, LA, RA, s1fA, s2fA, b0)
    EPILOGUE_B(1, SB, LB, RB, s1fB, s2fB, b1)

#undef HALO_B
#undef VSTEP_B
#undef EPILOGUE_B
}

extern "C" void kernel_launch(void* const* d_in, const int* in_sizes, int n_in,
                              void* d_out, int out_size, void* d_ws, size_t ws_size,
                              hipStream_t stream) {
    const float* X    = (const float*)d_in[0];
    const float* S1   = (const float*)d_in[1];
    const float* S2   = (const float*)d_in[2];
    const float* h_w  = (const float*)d_in[3];
    const float* h_b  = (const float*)d_in[4];
    const float* r_w  = (const float*)d_in[5];
    const float* q_w  = (const float*)d_in[6];
    const float* w    = (const float*)d_in[7];
    const float* fc_w = (const float*)d_in[8];
    float*       out  = (float*)d_out;
    float*       ws   = (float*)d_ws;

    vin_precompute<<<1, 256, 0, stream>>>(h_w, h_b, r_w, q_w, w, fc_w, ws);
    vin_kernel<<<B_N / 2, 64, 0, stream>>>(X, S1, S2, fc_w, ws, out);
}

// Round 19
// 31.251 us; speedup vs baseline: 1.0223x; 1.0223x over previous
//
#include <hip/hip_runtime.h>

#define B_N   2048
#define LQ    10
#define LH    150

typedef float pf2 __attribute__((ext_vector_type(2)));

// ws float layout:
//   [0..17] eff_w   [18] eff_b   [19..27] fw
//   [30..119]  qwpk: float2[45] {q_w[2ap][t], q_w[2ap+1][t]}, idx=ap*9+t
//   [120..209] wpk:  float2[45] {w[2ap][t],  w[2ap+1][t]},   idx=ap*9+t
#define QWPK 30
#define WPK  120

// ---------------- pre-kernel (1 block x 256 thr) — R16-verified ----------------
__global__ __launch_bounds__(256) void vin_precompute(
    const float* __restrict__ h_w, const float* __restrict__ h_b,
    const float* __restrict__ r_w, const float* __restrict__ q_w,
    const float* __restrict__ w,   const float* __restrict__ fc_w,
    float* __restrict__ ws)
{
    __shared__ float l[3000];   // [0,2700) h_w, [2700,2850) h_b, [2850,3000) r_w
    const int t = threadIdx.x;
    #pragma unroll
    for (int k = 0; k < 11; ++k) {
        int idx = t + (k << 8);
        if (idx < 2700) l[idx] = h_w[idx];
    }
    if (t < 150) { l[2700 + t] = h_b[t]; l[2850 + t] = r_w[t]; }
    __syncthreads();

    if (t < 152) {
        const int tap = t >> 3, j = t & 7;
        float acc = 0.f;
        for (int h = j; h < LH; h += 8)
            acc += l[2850 + h] * (tap < 18 ? l[h * 18 + tap] : l[2700 + h]);
        acc += __shfl_down(acc, 4, 8);
        acc += __shfl_down(acc, 2, 8);
        acc += __shfl_down(acc, 1, 8);
        if (j == 0) ws[tap] = acc;
    } else if (t < 161) {
        const int tt = t - 152;
        float acc = 0.f;
        #pragma unroll
        for (int a = 0; a < LQ; ++a) acc += fc_w[a] * w[a * 9 + tt];
        ws[19 + tt] = acc;
    } else if (t < 206) {
        const int idx = t - 161, ap = idx / 9, tt = idx - ap * 9;
        ws[QWPK + 2 * idx]     = q_w[(2 * ap)     * 9 + tt];
        ws[QWPK + 2 * idx + 1] = q_w[(2 * ap + 1) * 9 + tt];
    } else if (t < 251) {
        const int idx = t - 206, ap = idx / 9, tt = idx - ap * 9;
        ws[WPK + 2 * idx]     = w[(2 * ap)     * 9 + tt];
        ws[WPK + 2 * idx + 1] = w[(2 * ap + 1) * 9 + tt];
    }
}

// ---------------- main kernel ----------------
// ONE WAVE per batch element (2048 blocks x 64 thr, 2 waves/SIMD — the TLP
// cap for this problem size). lane = rg*16+c; rg owns rows 4rg..4rg+3, col c.
//
// R16 structure (register-resident barrier-free VI, DPP horizontal halo,
// 2 shfl vertical halo, action-pair v_pk_fma_f32) with ONE change:
// VI WEIGHTS ARE FORCED INTO VGPRs. R14-R18 all plateaued at VALUBusy ~35%
// regardless of TLP/ILP arrangement -> the common stall is in-loop s_load of
// the packed weights (hoisting needs ~180 SGPRs vs ~102 budget; SGPR_Count
// pegged at 112 every round). Fix: stage ws[30..209] into LDS, then
// broadcast ds_read_b64 the 45 w-pairs into pf2 wreg[45] (LDS->VGPR dest is
// architecturally VGPR; static indices keep it in registers, rule #20).
// VI-loop FMAs then have all-VGPR operands: zero in-loop memory traffic.
// LDS: X padded [0,1296) (ch*648+(row+1)*36+(col+1)); weights [1296,1476).
#define ST    36
#define WL_   1296
#define SMEMN 1476

__device__ __forceinline__ float dpp_left(float x) {   // col c-1; 0 at c==0
    return __int_as_float(__builtin_amdgcn_update_dpp(
        0, __float_as_int(x), 0x111, 0xF, 0xF, true));  // row_shr:1
}
__device__ __forceinline__ float dpp_right(float x) {  // col c+1; 0 at c==15
    return __int_as_float(__builtin_amdgcn_update_dpp(
        0, __float_as_int(x), 0x101, 0xF, 0xF, true));  // row_shl:1
}

__global__ __launch_bounds__(64, 2) void vin_kernel(
    const float* __restrict__ X,   const float* __restrict__ S1,
    const float* __restrict__ S2,  const float* __restrict__ fcw,
    const float* __restrict__ ws,  float* __restrict__ out)
{
    __shared__ float smem[SMEMN];

    const int lane = threadIdx.x;
    const int rg   = lane >> 4;
    const int c    = lane & 15;
    const int b    = blockIdx.x;

    // ---- issue all global loads first ----
    const float* Xb = X + (size_t)b * 512;
    float xreg[8];
    #pragma unroll
    for (int k = 0; k < 8; ++k) xreg[k] = Xb[lane + (k << 6)];
    const float s1f = S1[b], s2f = S2[b];

    // ---- collapsed weights via uniform s_loads (prologue-only use) ----
    float ew[19];
    #pragma unroll
    for (int tt = 0; tt < 19; ++tt) ew[tt] = ws[tt];

    // ---- stage packed weight tables into LDS (broadcast-read later) ----
    #pragma unroll
    for (int k = 0; k < 3; ++k) {
        int idx = lane + (k << 6);
        if (idx < 180) smem[WL_ + idx] = ws[30 + idx];
    }

    // ---- zero ONLY the read-border cells of X (disjoint from interior) ----
    #pragma unroll
    for (int ch = 0; ch < 2; ++ch) {
        float* Bc = smem + ch * 648;
        if (lane < 18)      { Bc[lane] = 0.f; Bc[17 * ST + lane] = 0.f; }
        else if (lane < 34) { const int r = lane - 17; Bc[r * ST] = 0.f; Bc[r * ST + 17] = 0.f; }
    }

    // ---- stage X (interior cells only) ----
    #pragma unroll
    for (int k = 0; k < 8; ++k) {
        int e = lane + (k << 6);
        int ch = e >> 8, rem = e & 255;
        smem[ch * 648 + ((rem >> 4) + 1) * ST + (rem & 15) + 1] = xreg[k];
    }
    __syncthreads();                       // single prologue barrier

    // ---- r = conv3x3(X, eff_w) + eff_b for this lane's 4 rows (in regs) ----
    float rr0, rr1, rr2, rr3;
    {
        const float* xb = smem + (rg << 2) * ST + c;
        float xt[2][6][3];
        #pragma unroll
        for (int ch = 0; ch < 2; ++ch)
            #pragma unroll
            for (int dy = 0; dy < 6; ++dy)
                #pragma unroll
                for (int dx = 0; dx < 3; ++dx)
                    xt[ch][dy][dx] = xb[ch * 648 + dy * ST + dx];

        #pragma unroll
        for (int k = 0; k < 4; ++k) {
            float acc = ew[18];
            #pragma unroll
            for (int ch = 0; ch < 2; ++ch)
                #pragma unroll
                for (int ky = 0; ky < 3; ++ky)
                    #pragma unroll
                    for (int kx = 0; kx < 3; ++kx)
                        acc += xt[ch][k + ky][kx] * ew[ch * 9 + ky * 3 + kx];
            if (k == 0) rr0 = acc; else if (k == 1) rr1 = acc;
            else if (k == 2) rr2 = acc; else rr3 = acc;
        }
    }

    const bool top0 = (rg == 0), bot0 = (rg == 3);
    const int  upL  = (lane - 16) & 63;
    const int  dnL  = (lane + 16) & 63;

    // ---- r halo via shuffle machinery (no LDS round-trip) ----
    float S[6], L[6], R[6];
    {
        float t_ = __shfl(rr3, upL, 64);
        float b_ = __shfl(rr0, dnL, 64);
        S[0] = top0 ? 0.f : t_;
        S[1] = rr0; S[2] = rr1; S[3] = rr2; S[4] = rr3;
        S[5] = bot0 ? 0.f : b_;
        #pragma unroll
        for (int j = 0; j < 6; ++j) { L[j] = dpp_left(S[j]); R[j] = dpp_right(S[j]); }
    }

    // ---- qr2[k][ap] = packed conv3x3(r, q_w): q-weights via LDS (one-time) ----
    const pf2* qwp  = (const pf2*)&smem[WL_];        // 45 pairs
    const pf2* wlds = (const pf2*)&smem[WL_ + 90];   // 45 pairs

    pf2 qr2[4][5];
    #pragma unroll
    for (int k = 0; k < 4; ++k)
        #pragma unroll
        for (int ap = 0; ap < 5; ++ap) {
            pf2 acc = {0.f, 0.f};
            #pragma unroll
            for (int dy = 0; dy < 3; ++dy) {
                const float tl = L[k + dy], ts = S[k + dy], tr = R[k + dy];
                pf2 vl = {tl, tl}, vs = {ts, ts}, vr = {tr, tr};
                acc = __builtin_elementwise_fma(vl, qwp[ap * 9 + dy * 3 + 0], acc);
                acc = __builtin_elementwise_fma(vs, qwp[ap * 9 + dy * 3 + 1], acc);
                acc = __builtin_elementwise_fma(vr, qwp[ap * 9 + dy * 3 + 2], acc);
            }
            qr2[k][ap] = acc;
        }

    // ---- VI weights -> VGPR-resident pf2 array (the round-19 change) ----
    pf2 wreg[45];
    #pragma unroll
    for (int t = 0; t < 45; ++t) wreg[t] = wlds[t];

    // ---- v0 = max over 10 actions, register-resident ----
    float vv0, vv1, vv2, vv3;
    {
        pf2 m0 = __builtin_elementwise_max(
                     __builtin_elementwise_max(qr2[0][0], qr2[0][1]),
                     __builtin_elementwise_max(qr2[0][2], qr2[0][3]));
        m0 = __builtin_elementwise_max(m0, qr2[0][4]);
        vv0 = fmaxf(m0.x, m0.y);
        pf2 m1 = __builtin_elementwise_max(
                     __builtin_elementwise_max(qr2[1][0], qr2[1][1]),
                     __builtin_elementwise_max(qr2[1][2], qr2[1][3]));
        m1 = __builtin_elementwise_max(m1, qr2[1][4]);
        vv1 = fmaxf(m1.x, m1.y);
        pf2 m2 = __builtin_elementwise_max(
                     __builtin_elementwise_max(qr2[2][0], qr2[2][1]),
                     __builtin_elementwise_max(qr2[2][2], qr2[2][3]));
        m2 = __builtin_elementwise_max(m2, qr2[2][4]);
        vv2 = fmaxf(m2.x, m2.y);
        pf2 m3 = __builtin_elementwise_max(
                     __builtin_elementwise_max(qr2[3][0], qr2[3][1]),
                     __builtin_elementwise_max(qr2[3][2], qr2[3][3]));
        m3 = __builtin_elementwise_max(m3, qr2[3][4]);
        vv3 = fmaxf(m3.x, m3.y);
    }

    // S[j] = own-column v at pixel row 4rg-1+j; L/R = cols c-1/c+1 via DPP.
#define HALO()                                                       \
    {                                                                \
        float t_ = __shfl(vv3, upL, 64);                             \
        float b_ = __shfl(vv0, dnL, 64);                             \
        S[0] = top0 ? 0.f : t_;                                      \
        S[1] = vv0; S[2] = vv1; S[3] = vv2; S[4] = vv3;              \
        S[5] = bot0 ? 0.f : b_;                                      \
        _Pragma("unroll")                                            \
        for (int j = 0; j < 6; ++j) {                                \
            L[j] = dpp_left(S[j]);                                   \
            R[j] = dpp_right(S[j]);                                  \
        }                                                            \
    }

    // ---- 19 VI sweeps: barrier-free, memory-free (all-VGPR operands) ----
    #pragma unroll 1
    for (int it = 0; it < 19; ++it) {
        HALO();
        #pragma unroll
        for (int k = 0; k < 4; ++k) {
            pf2 a_[5];
            #pragma unroll
            for (int ap = 0; ap < 5; ++ap) a_[ap] = qr2[k][ap];
            #pragma unroll
            for (int dy = 0; dy < 3; ++dy) {
                const float tl = L[k + dy], ts = S[k + dy], tr = R[k + dy];
                pf2 vl = {tl, tl}, vs = {ts, ts}, vr = {tr, tr};
                #pragma unroll
                for (int ap = 0; ap < 5; ++ap) {
                    a_[ap] = __builtin_elementwise_fma(vl, wreg[ap * 9 + dy * 3 + 0], a_[ap]);
                    a_[ap] = __builtin_elementwise_fma(vs, wreg[ap * 9 + dy * 3 + 1], a_[ap]);
                    a_[ap] = __builtin_elementwise_fma(vr, wreg[ap * 9 + dy * 3 + 2], a_[ap]);
                }
            }
            pf2 m = __builtin_elementwise_max(
                        __builtin_elementwise_max(a_[0], a_[1]),
                        __builtin_elementwise_max(a_[2], a_[3]));
            m = __builtin_elementwise_max(m, a_[4]);
            float mk = fmaxf(m.x, m.y);
            if (k == 0) vv0 = mk; else if (k == 1) vv1 = mk;
            else if (k == 2) vv2 = mk; else vv3 = mk;
        }
    }

    // ---- one more halo for the final conv's v-taps ----
    HALO();

    // ---- final conv + gather + fc at (s1, s2) only ----
    int s1 = (int)floorf((s1f + 50.0f) / 6.25f);
    int s2 = (int)floorf((s2f + 50.0f) / 6.25f);
    s1 = min(max(s1, 0), 15);
    s2 = min(max(s2, 0), 15);

    if (rg == (s1 >> 2) && c == s2) {
        float fw[9];
        #pragma unroll
        for (int tt = 0; tt < 9; ++tt) fw[tt] = ws[19 + tt];

        float d0, d1, d2, d3;
        {
            pf2 p0 = {0.f, 0.f}, p1 = p0, p2 = p0, p3 = p0;
            #pragma unroll
            for (int ap = 0; ap < 5; ++ap) {
                const pf2 fcp = *(const pf2*)(fcw + 2 * ap);
                p0 = __builtin_elementwise_fma(qr2[0][ap], fcp, p0);
                p1 = __builtin_elementwise_fma(qr2[1][ap], fcp, p1);
                p2 = __builtin_elementwise_fma(qr2[2][ap], fcp, p2);
                p3 = __builtin_elementwise_fma(qr2[3][ap], fcp, p3);
            }
            d0 = p0.x + p0.y; d1 = p1.x + p1.y;
            d2 = p2.x + p2.y; d3 = p3.x + p3.y;
        }
        float g0 = d0, g1 = d1, g2 = d2, g3 = d3;
        #pragma unroll
        for (int dy = 0; dy < 3; ++dy) {
            const float f0 = fw[dy * 3 + 0], f1 = fw[dy * 3 + 1], f2 = fw[dy * 3 + 2];
            g0 += L[0 + dy] * f0; g0 += S[0 + dy] * f1; g0 += R[0 + dy] * f2;
            g1 += L[1 + dy] * f0; g1 += S[1 + dy] * f1; g1 += R[1 + dy] * f2;
            g2 += L[2 + dy] * f0; g2 += S[2 + dy] * f1; g2 += R[2 + dy] * f2;
            g3 += L[3 + dy] * f0; g3 += S[3 + dy] * f1; g3 += R[3 + dy] * f2;
        }
        const int kk = s1 & 3;
        float logit = (kk == 0) ? g0 : (kk == 1) ? g1 : (kk == 2) ? g2 : g3;
        out[b]       = logit;   // logits
        out[B_N + b] = 1.0f;    // softmax over length-1 axis == 1
    }
#undef HALO
}

extern "C" void kernel_launch(void* const* d_in, const int* in_sizes, int n_in,
                              void* d_out, int out_size, void* d_ws, size_t ws_size,
                              hipStream_t stream) {
    const float* X    = (const float*)d_in[0];
    const float* S1   = (const float*)d_in[1];
    const float* S2   = (const float*)d_in[2];
    const float* h_w  = (const float*)d_in[3];
    const float* h_b  = (const float*)d_in[4];
    const float* r_w  = (const float*)d_in[5];
    const float* q_w  = (const float*)d_in[6];
    const float* w    = (const float*)d_in[7];
    const float* fc_w = (const float*)d_in[8];
    float*       out  = (float*)d_out;
    float*       ws   = (float*)d_ws;

    vin_precompute<<<1, 256, 0, stream>>>(h_w, h_b, r_w, q_w, w, fc_w, ws);
    vin_kernel<<<B_N, 64, 0, stream>>>(X, S1, S2, fc_w, ws, out);
}